// Round 3
// baseline (424.396 us; speedup 1.0000x reference)
//
#include <hip/hip_runtime.h>
#include <math.h>
#include <stdint.h>

#define DD 32
// group record: 56 u32 words (224B): words[0..7]=s[16] bf16, words[8..55]=me[3][32] bf16
// item  record: 24 u32 words (96B):  words[0..7]=t[16] bf16, words[8..23]=ie[32] bf16
#define GRECW 56
#define IRECW 24

__device__ __forceinline__ uint32_t bf16rne(float f) {
    uint32_t u = __float_as_uint(f);
    return (u + 0x7fffu + ((u >> 16) & 1u)) >> 16;
}
__device__ __forceinline__ uint32_t pack2(float a, float b) {
    return bf16rne(a) | (bf16rne(b) << 16);
}
#define BLO(u) __uint_as_float((u) << 16)
#define BHI(u) __uint_as_float((u) & 0xffff0000u)

// ---------------- zero the histogram ----------------
__global__ __launch_bounds__(256) void zero_cnt(int* __restrict__ cnt, int n) {
    int i = blockIdx.x * 256 + threadIdx.x;
    if (i < n) cnt[i] = 0;
}

// ---------------- histogram of group ids ----------------
__global__ __launch_bounds__(256) void hist_kernel(
    const int* __restrict__ gi, int* __restrict__ cnt, int B)
{
    int b = blockIdx.x * 256 + threadIdx.x;
    if (b < B) atomicAdd(&cnt[gi[b]], 1);
}

// ---------------- single-block exclusive scan over NG bins ----------------
__global__ __launch_bounds__(1024) void scan_kernel(
    const int* __restrict__ cnt, int* __restrict__ base, int NG)
{
    __shared__ int part[1024];
    int t = threadIdx.x;
    int C = (NG + 1023) / 1024;
    int lo = t * C, hi = min(lo + C, NG);
    int s = 0;
    for (int i = lo; i < hi; ++i) s += cnt[i];
    part[t] = s;
    __syncthreads();
    for (int off = 1; off < 1024; off <<= 1) {
        int add = (t >= off) ? part[t - off] : 0;
        int v = part[t];
        __syncthreads();
        part[t] = v + add;
        __syncthreads();
    }
    int run = (t == 0) ? 0 : part[t - 1];
    for (int i = lo; i < hi; ++i) { base[i] = run; run += cnt[i]; }
}

// ---------------- scatter: keys[pos] = (g, item, b) sorted by g ----------------
__global__ __launch_bounds__(256) void scatter_kernel(
    const int* __restrict__ gi, const int* __restrict__ ii,
    int* __restrict__ base, int4* __restrict__ keys, int B)
{
    int b = blockIdx.x * 256 + threadIdx.x;
    if (b >= B) return;
    int g = gi[b];
    int pos = atomicAdd(&base[g], 1);
    keys[pos] = make_int4(g, ii[b], b, 0);
}

// ---------------- group precompute: 4 threads per group ----------------
__global__ __launch_bounds__(256) void grp_pre(
    const int* __restrict__ gm, const float* __restrict__ ue,
    const float* __restrict__ w1, const float* __restrict__ b1,
    uint32_t* __restrict__ grec, int NG)
{
    int tid = blockIdx.x * 256 + threadIdx.x;
    int g = tid >> 2, q = tid & 3;
    if (g >= NG) return;
    uint32_t* rec = grec + (size_t)g * GRECW;

    int u0 = gm[3 * g + 0], u1 = gm[3 * g + 1], u2 = gm[3 * g + 2];
    float me[96];
    {
        const float4* p0 = reinterpret_cast<const float4*>(ue + (size_t)u0 * DD);
        const float4* p1 = reinterpret_cast<const float4*>(ue + (size_t)u1 * DD);
        const float4* p2 = reinterpret_cast<const float4*>(ue + (size_t)u2 * DD);
        #pragma unroll
        for (int c = 0; c < 8; ++c) {
            float4 v0 = p0[c], v1 = p1[c], v2 = p2[c];
            me[4*c+0]    = v0.x; me[4*c+1]    = v0.y; me[4*c+2]    = v0.z; me[4*c+3]    = v0.w;
            me[32+4*c+0] = v1.x; me[32+4*c+1] = v1.y; me[32+4*c+2] = v1.z; me[32+4*c+3] = v1.w;
            me[64+4*c+0] = v2.x; me[64+4*c+1] = v2.y; me[64+4*c+2] = v2.z; me[64+4*c+3] = v2.w;
        }
    }
    // this thread computes s[4q .. 4q+3]
    float s0 = b1[4*q+0], s1 = b1[4*q+1], s2 = b1[4*q+2], s3 = b1[4*q+3];
    #pragma unroll
    for (int d = 0; d < 96; ++d) {
        float x = me[d];
        const float4 wv = *reinterpret_cast<const float4*>(w1 + d * 16 + 4 * q);
        s0 = fmaf(x, wv.x, s0);
        s1 = fmaf(x, wv.y, s1);
        s2 = fmaf(x, wv.z, s2);
        s3 = fmaf(x, wv.w, s3);
    }
    uint2 sw;
    sw.x = pack2(s0, s1);
    sw.y = pack2(s2, s3);
    *reinterpret_cast<uint2*>(rec + 2 * q) = sw;

    // threads 1..3 convert member q-1 to bf16
    if (q >= 1) {
        int m = q - 1;
        const float* src = me + 32 * m;
        uint32_t* dst = rec + 8 + 16 * m;
        #pragma unroll
        for (int c = 0; c < 4; ++c) {
            uint4 o;
            o.x = pack2(src[8*c+0], src[8*c+1]);
            o.y = pack2(src[8*c+2], src[8*c+3]);
            o.z = pack2(src[8*c+4], src[8*c+5]);
            o.w = pack2(src[8*c+6], src[8*c+7]);
            *reinterpret_cast<uint4*>(dst + 4 * c) = o;
        }
    }
}

// ---------------- item precompute: 2 threads per item ----------------
__global__ __launch_bounds__(256) void item_pre(
    const float* __restrict__ itemb, const float* __restrict__ w1,
    uint32_t* __restrict__ irec, int NI)
{
    int tid = blockIdx.x * 256 + threadIdx.x;
    int i = tid >> 1, q = tid & 1;
    if (i >= NI) return;
    uint32_t* rec = irec + (size_t)i * IRECW;

    float ev[32];
    {
        const float4* p = reinterpret_cast<const float4*>(itemb + (size_t)i * DD);
        #pragma unroll
        for (int c = 0; c < 8; ++c) {
            float4 v = p[c];
            ev[4*c+0] = v.x; ev[4*c+1] = v.y; ev[4*c+2] = v.z; ev[4*c+3] = v.w;
        }
    }
    // this thread computes t[8q .. 8q+7]  (w1 rows 96..127)
    float tt[8];
    #pragma unroll
    for (int j = 0; j < 8; ++j) tt[j] = 0.0f;
    #pragma unroll
    for (int d = 0; d < 32; ++d) {
        float x = ev[d];
        const float4 wa = *reinterpret_cast<const float4*>(w1 + (96 + d) * 16 + 8 * q);
        const float4 wb = *reinterpret_cast<const float4*>(w1 + (96 + d) * 16 + 8 * q + 4);
        tt[0] = fmaf(x, wa.x, tt[0]); tt[1] = fmaf(x, wa.y, tt[1]);
        tt[2] = fmaf(x, wa.z, tt[2]); tt[3] = fmaf(x, wa.w, tt[3]);
        tt[4] = fmaf(x, wb.x, tt[4]); tt[5] = fmaf(x, wb.y, tt[5]);
        tt[6] = fmaf(x, wb.z, tt[6]); tt[7] = fmaf(x, wb.w, tt[7]);
    }
    uint4 tw;
    tw.x = pack2(tt[0], tt[1]); tw.y = pack2(tt[2], tt[3]);
    tw.z = pack2(tt[4], tt[5]); tw.w = pack2(tt[6], tt[7]);
    *reinterpret_cast<uint4*>(rec + 4 * q) = tw;

    // thread q converts ie floats [16q .. 16q+15] -> words 8+8q ..
    {
        const float* src = ev + 16 * q;
        uint32_t* dst = rec + 8 + 8 * q;
        #pragma unroll
        for (int c = 0; c < 2; ++c) {
            uint4 o;
            o.x = pack2(src[8*c+0], src[8*c+1]);
            o.y = pack2(src[8*c+2], src[8*c+3]);
            o.z = pack2(src[8*c+4], src[8*c+5]);
            o.w = pack2(src[8*c+6], src[8*c+7]);
            *reinterpret_cast<uint4*>(dst + 4 * c) = o;
        }
    }
}

// ---------------- main: one thread per batch element, group-sorted ----------------
__global__ __launch_bounds__(256) void agree_main(
    const int4* __restrict__ keys,
    const uint32_t* __restrict__ grec, const uint32_t* __restrict__ irec,
    const float* __restrict__ w2, const float* __restrict__ b2,
    const float* __restrict__ pw1, const float* __restrict__ pb1,
    const float* __restrict__ pw2, const float* __restrict__ pb2,
    float* __restrict__ out, int B)
{
    int t = blockIdx.x * 256 + threadIdx.x;
    if (t >= B) return;
    int4 k = keys[t];
    const uint32_t* gr = grec + (size_t)k.x * GRECW;
    const uint32_t* ir = irec + (size_t)k.y * IRECW;

    // h = relu(s + t)
    float h[16];
    #pragma unroll
    for (int c = 0; c < 2; ++c) {
        uint4 sa = *reinterpret_cast<const uint4*>(gr + 4 * c);
        uint4 ta = *reinterpret_cast<const uint4*>(ir + 4 * c);
        h[8*c+0] = fmaxf(BLO(sa.x) + BLO(ta.x), 0.0f);
        h[8*c+1] = fmaxf(BHI(sa.x) + BHI(ta.x), 0.0f);
        h[8*c+2] = fmaxf(BLO(sa.y) + BLO(ta.y), 0.0f);
        h[8*c+3] = fmaxf(BHI(sa.y) + BHI(ta.y), 0.0f);
        h[8*c+4] = fmaxf(BLO(sa.z) + BLO(ta.z), 0.0f);
        h[8*c+5] = fmaxf(BHI(sa.z) + BHI(ta.z), 0.0f);
        h[8*c+6] = fmaxf(BLO(sa.w) + BLO(ta.w), 0.0f);
        h[8*c+7] = fmaxf(BHI(sa.w) + BHI(ta.w), 0.0f);
    }

    // logits + softmax over 3 members
    float l0 = b2[0], l1 = b2[1], l2 = b2[2];
    #pragma unroll
    for (int j = 0; j < 16; ++j) {
        l0 = fmaf(h[j], w2[j * 3 + 0], l0);
        l1 = fmaf(h[j], w2[j * 3 + 1], l1);
        l2 = fmaf(h[j], w2[j * 3 + 2], l2);
    }
    float mx = fmaxf(l0, fmaxf(l1, l2));
    float e0 = __expf(l0 - mx);
    float e1 = __expf(l1 - mx);
    float e2 = __expf(l2 - mx);
    float inv = 1.0f / (e0 + e1 + e2);
    float wt0 = e0 * inv, wt1 = e1 * inv, wt2 = e2 * inv;

    // g = wt0*me0 + wt1*me1 + wt2*me2   (decode bf16 on the fly)
    float g[32];
    #pragma unroll
    for (int c = 0; c < 4; ++c) {
        uint4 a = *reinterpret_cast<const uint4*>(gr + 8  + 4 * c);
        uint4 bq = *reinterpret_cast<const uint4*>(gr + 24 + 4 * c);
        uint4 cq = *reinterpret_cast<const uint4*>(gr + 40 + 4 * c);
        g[8*c+0] = fmaf(wt0, BLO(a.x), fmaf(wt1, BLO(bq.x), wt2 * BLO(cq.x)));
        g[8*c+1] = fmaf(wt0, BHI(a.x), fmaf(wt1, BHI(bq.x), wt2 * BHI(cq.x)));
        g[8*c+2] = fmaf(wt0, BLO(a.y), fmaf(wt1, BLO(bq.y), wt2 * BLO(cq.y)));
        g[8*c+3] = fmaf(wt0, BHI(a.y), fmaf(wt1, BHI(bq.y), wt2 * BHI(cq.y)));
        g[8*c+4] = fmaf(wt0, BLO(a.z), fmaf(wt1, BLO(bq.z), wt2 * BLO(cq.z)));
        g[8*c+5] = fmaf(wt0, BHI(a.z), fmaf(wt1, BHI(bq.z), wt2 * BHI(cq.z)));
        g[8*c+6] = fmaf(wt0, BLO(a.w), fmaf(wt1, BLO(bq.w), wt2 * BLO(cq.w)));
        g[8*c+7] = fmaf(wt0, BHI(a.w), fmaf(wt1, BHI(bq.w), wt2 * BHI(cq.w)));
    }

    // h2[j] = pb1[j] + (g.*ie)@A + g@B + ie@C   (A=pw1 rows 0..31, B=32..63, C=64..95)
    float h2[8];
    #pragma unroll
    for (int j = 0; j < 8; ++j) h2[j] = pb1[j];

    #pragma unroll
    for (int c = 0; c < 4; ++c) {
        uint4 e4 = *reinterpret_cast<const uint4*>(ir + 8 + 4 * c);
        float ef[8];
        ef[0] = BLO(e4.x); ef[1] = BHI(e4.x);
        ef[2] = BLO(e4.y); ef[3] = BHI(e4.y);
        ef[4] = BLO(e4.z); ef[5] = BHI(e4.z);
        ef[6] = BLO(e4.w); ef[7] = BHI(e4.w);
        #pragma unroll
        for (int r = 0; r < 8; ++r) {
            int d = 8 * c + r;
            float e  = ef[r];
            float gd = g[d];
            float ge = gd * e;
            #pragma unroll
            for (int j = 0; j < 8; ++j) {
                h2[j] = fmaf(ge, pw1[d * 8 + j],        h2[j]);
                h2[j] = fmaf(gd, pw1[(32 + d) * 8 + j], h2[j]);
                h2[j] = fmaf(e,  pw1[(64 + d) * 8 + j], h2[j]);
            }
        }
    }

    float z = pb2[0];
    #pragma unroll
    for (int j = 0; j < 8; ++j)
        z = fmaf(fmaxf(h2[j], 0.0f), pw2[j], z);

    out[k.z] = 1.0f / (1.0f + __expf(-z));
}

// ---------------- fallback (round-1 kernel) if ws too small ----------------
__global__ __launch_bounds__(256) void agree_fwd(
    const int* __restrict__ gi, const int* __restrict__ ii,
    const int* __restrict__ gm,
    const float* __restrict__ ue, const float* __restrict__ itemb,
    const float* __restrict__ w1, const float* __restrict__ b1,
    const float* __restrict__ w2, const float* __restrict__ b2,
    const float* __restrict__ pw1, const float* __restrict__ pb1,
    const float* __restrict__ pw2, const float* __restrict__ pb2,
    float* __restrict__ out, int B)
{
    int b = blockIdx.x * blockDim.x + threadIdx.x;
    if (b >= B) return;
    int g = gi[b], it = ii[b];
    int m0 = gm[3*g+0], m1 = gm[3*g+1], m2 = gm[3*g+2];
    float me[3][DD], iev[DD];
    {
        const float4* p0 = reinterpret_cast<const float4*>(ue + (size_t)m0 * DD);
        const float4* p1 = reinterpret_cast<const float4*>(ue + (size_t)m1 * DD);
        const float4* p2 = reinterpret_cast<const float4*>(ue + (size_t)m2 * DD);
        const float4* p3 = reinterpret_cast<const float4*>(itemb + (size_t)it * DD);
        #pragma unroll
        for (int c = 0; c < 8; ++c) {
            float4 v0 = p0[c], v1 = p1[c], v2 = p2[c], v3 = p3[c];
            me[0][4*c]=v0.x; me[0][4*c+1]=v0.y; me[0][4*c+2]=v0.z; me[0][4*c+3]=v0.w;
            me[1][4*c]=v1.x; me[1][4*c+1]=v1.y; me[1][4*c+2]=v1.z; me[1][4*c+3]=v1.w;
            me[2][4*c]=v2.x; me[2][4*c+1]=v2.y; me[2][4*c+2]=v2.z; me[2][4*c+3]=v2.w;
            iev[4*c]=v3.x; iev[4*c+1]=v3.y; iev[4*c+2]=v3.z; iev[4*c+3]=v3.w;
        }
    }
    float h[16];
    #pragma unroll
    for (int j = 0; j < 16; ++j) h[j] = b1[j];
    #pragma unroll
    for (int m = 0; m < 3; ++m)
        #pragma unroll
        for (int kk = 0; kk < DD; ++kk) {
            float xk = me[m][kk];
            #pragma unroll
            for (int j = 0; j < 16; ++j)
                h[j] = fmaf(xk, w1[(m*DD+kk)*16+j], h[j]);
        }
    #pragma unroll
    for (int kk = 0; kk < DD; ++kk) {
        float xk = iev[kk];
        #pragma unroll
        for (int j = 0; j < 16; ++j)
            h[j] = fmaf(xk, w1[(3*DD+kk)*16+j], h[j]);
    }
    #pragma unroll
    for (int j = 0; j < 16; ++j) h[j] = fmaxf(h[j], 0.0f);
    float l0 = b2[0], l1 = b2[1], l2 = b2[2];
    #pragma unroll
    for (int j = 0; j < 16; ++j) {
        l0 = fmaf(h[j], w2[j*3+0], l0);
        l1 = fmaf(h[j], w2[j*3+1], l1);
        l2 = fmaf(h[j], w2[j*3+2], l2);
    }
    float mx = fmaxf(l0, fmaxf(l1, l2));
    float e0 = __expf(l0-mx), e1 = __expf(l1-mx), e2 = __expf(l2-mx);
    float inv = 1.0f / (e0+e1+e2);
    float wt0 = e0*inv, wt1 = e1*inv, wt2 = e2*inv;
    float h2[8];
    #pragma unroll
    for (int j = 0; j < 8; ++j) h2[j] = pb1[j];
    #pragma unroll
    for (int d = 0; d < DD; ++d) {
        float gd  = wt0*me[0][d] + wt1*me[1][d] + wt2*me[2][d];
        float gie = gd * iev[d];
        #pragma unroll
        for (int j = 0; j < 8; ++j) {
            h2[j] = fmaf(gie,    pw1[d*8+j],          h2[j]);
            h2[j] = fmaf(gd,     pw1[(DD+d)*8+j],     h2[j]);
            h2[j] = fmaf(iev[d], pw1[(2*DD+d)*8+j],   h2[j]);
        }
    }
    float z = pb2[0];
    #pragma unroll
    for (int j = 0; j < 8; ++j)
        z = fmaf(fmaxf(h2[j], 0.0f), pw2[j], z);
    out[b] = 1.0f / (1.0f + __expf(-z));
}

extern "C" void kernel_launch(void* const* d_in, const int* in_sizes, int n_in,
                              void* d_out, int out_size, void* d_ws, size_t ws_size,
                              hipStream_t stream) {
    const int*   gi    = (const int*)d_in[0];
    const int*   ii    = (const int*)d_in[1];
    const int*   gm    = (const int*)d_in[2];
    const float* ue    = (const float*)d_in[3];
    const float* itemb = (const float*)d_in[4];
    const float* w1    = (const float*)d_in[5];
    const float* b1    = (const float*)d_in[6];
    const float* w2    = (const float*)d_in[7];
    const float* b2    = (const float*)d_in[8];
    const float* pw1   = (const float*)d_in[9];
    const float* pb1   = (const float*)d_in[10];
    const float* pw2   = (const float*)d_in[11];
    const float* pb2   = (const float*)d_in[12];
    float* out = (float*)d_out;

    int B  = in_sizes[0];
    int NG = in_sizes[2] / 3;
    int NI = in_sizes[4] / DD;

    // workspace layout (256B-aligned segments)
    size_t off = 0;
    auto alloc = [&](size_t bytes) {
        size_t o = off;
        off += (bytes + 255) & ~(size_t)255;
        return o;
    };
    size_t o_grec = alloc((size_t)NG * GRECW * 4);
    size_t o_irec = alloc((size_t)NI * IRECW * 4);
    size_t o_cnt  = alloc((size_t)NG * 4);
    size_t o_base = alloc((size_t)NG * 4);
    size_t o_keys = alloc((size_t)B * 16);

    if (ws_size >= off) {
        char* ws = (char*)d_ws;
        uint32_t* grec = (uint32_t*)(ws + o_grec);
        uint32_t* irec = (uint32_t*)(ws + o_irec);
        int*      cnt  = (int*)(ws + o_cnt);
        int*      base = (int*)(ws + o_base);
        int4*     keys = (int4*)(ws + o_keys);

        hipLaunchKernelGGL(zero_cnt, dim3((NG + 255) / 256), dim3(256), 0, stream, cnt, NG);
        hipLaunchKernelGGL(hist_kernel, dim3((B + 255) / 256), dim3(256), 0, stream, gi, cnt, B);
        hipLaunchKernelGGL(scan_kernel, dim3(1), dim3(1024), 0, stream, cnt, base, NG);
        hipLaunchKernelGGL(scatter_kernel, dim3((B + 255) / 256), dim3(256), 0, stream,
                           gi, ii, base, keys, B);
        hipLaunchKernelGGL(grp_pre, dim3((4 * NG + 255) / 256), dim3(256), 0, stream,
                           gm, ue, w1, b1, grec, NG);
        hipLaunchKernelGGL(item_pre, dim3((2 * NI + 255) / 256), dim3(256), 0, stream,
                           itemb, w1, irec, NI);
        hipLaunchKernelGGL(agree_main, dim3((B + 255) / 256), dim3(256), 0, stream,
                           keys, grec, irec, w2, b2, pw1, pb1, pw2, pb2, out, B);
    } else {
        hipLaunchKernelGGL(agree_fwd, dim3((B + 255) / 256), dim3(256), 0, stream,
                           gi, ii, gm, ue, itemb, w1, b1, w2, b2,
                           pw1, pb1, pw2, pb2, out, B);
    }
}

// Round 4
// 250.037 us; speedup vs baseline: 1.6973x; 1.6973x over previous
//
#include <hip/hip_runtime.h>
#include <math.h>
#include <stdint.h>

#define DD 32
// group record: 56 u32 words (224B): words[0..7]=s[16] bf16, words[8..55]=me[3][32] bf16
// item  record: 24 u32 words (96B):  words[0..7]=t[16] bf16, words[8..23]=ie[32] bf16
#define GRECW 56
#define IRECW 24

__device__ __forceinline__ uint32_t bf16rne(float f) {
    uint32_t u = __float_as_uint(f);
    return (u + 0x7fffu + ((u >> 16) & 1u)) >> 16;
}
__device__ __forceinline__ uint32_t pack2(float a, float b) {
    return bf16rne(a) | (bf16rne(b) << 16);
}
#define BLO(u) __uint_as_float((u) << 16)
#define BHI(u) __uint_as_float((u) & 0xffff0000u)

// ---------------- group precompute: 4 threads per group ----------------
__global__ __launch_bounds__(256) void grp_pre(
    const int* __restrict__ gm, const float* __restrict__ ue,
    const float* __restrict__ w1, const float* __restrict__ b1,
    uint32_t* __restrict__ grec, int NG)
{
    int tid = blockIdx.x * 256 + threadIdx.x;
    int g = tid >> 2, q = tid & 3;
    if (g >= NG) return;
    uint32_t* rec = grec + (size_t)g * GRECW;

    int u0 = gm[3 * g + 0], u1 = gm[3 * g + 1], u2 = gm[3 * g + 2];
    float me[96];
    {
        const float4* p0 = reinterpret_cast<const float4*>(ue + (size_t)u0 * DD);
        const float4* p1 = reinterpret_cast<const float4*>(ue + (size_t)u1 * DD);
        const float4* p2 = reinterpret_cast<const float4*>(ue + (size_t)u2 * DD);
        #pragma unroll
        for (int c = 0; c < 8; ++c) {
            float4 v0 = p0[c], v1 = p1[c], v2 = p2[c];
            me[4*c+0]    = v0.x; me[4*c+1]    = v0.y; me[4*c+2]    = v0.z; me[4*c+3]    = v0.w;
            me[32+4*c+0] = v1.x; me[32+4*c+1] = v1.y; me[32+4*c+2] = v1.z; me[32+4*c+3] = v1.w;
            me[64+4*c+0] = v2.x; me[64+4*c+1] = v2.y; me[64+4*c+2] = v2.z; me[64+4*c+3] = v2.w;
        }
    }
    // this thread computes s[4q .. 4q+3]
    float s0 = b1[4*q+0], s1 = b1[4*q+1], s2 = b1[4*q+2], s3 = b1[4*q+3];
    #pragma unroll
    for (int d = 0; d < 96; ++d) {
        float x = me[d];
        const float4 wv = *reinterpret_cast<const float4*>(w1 + d * 16 + 4 * q);
        s0 = fmaf(x, wv.x, s0);
        s1 = fmaf(x, wv.y, s1);
        s2 = fmaf(x, wv.z, s2);
        s3 = fmaf(x, wv.w, s3);
    }
    uint2 sw;
    sw.x = pack2(s0, s1);
    sw.y = pack2(s2, s3);
    *reinterpret_cast<uint2*>(rec + 2 * q) = sw;

    // threads 1..3 convert member q-1 to bf16
    if (q >= 1) {
        int m = q - 1;
        const float* src = me + 32 * m;
        uint32_t* dst = rec + 8 + 16 * m;
        #pragma unroll
        for (int c = 0; c < 4; ++c) {
            uint4 o;
            o.x = pack2(src[8*c+0], src[8*c+1]);
            o.y = pack2(src[8*c+2], src[8*c+3]);
            o.z = pack2(src[8*c+4], src[8*c+5]);
            o.w = pack2(src[8*c+6], src[8*c+7]);
            *reinterpret_cast<uint4*>(dst + 4 * c) = o;
        }
    }
}

// ---------------- item precompute: 2 threads per item ----------------
__global__ __launch_bounds__(256) void item_pre(
    const float* __restrict__ itemb, const float* __restrict__ w1,
    uint32_t* __restrict__ irec, int NI)
{
    int tid = blockIdx.x * 256 + threadIdx.x;
    int i = tid >> 1, q = tid & 1;
    if (i >= NI) return;
    uint32_t* rec = irec + (size_t)i * IRECW;

    float ev[32];
    {
        const float4* p = reinterpret_cast<const float4*>(itemb + (size_t)i * DD);
        #pragma unroll
        for (int c = 0; c < 8; ++c) {
            float4 v = p[c];
            ev[4*c+0] = v.x; ev[4*c+1] = v.y; ev[4*c+2] = v.z; ev[4*c+3] = v.w;
        }
    }
    // this thread computes t[8q .. 8q+7]  (w1 rows 96..127)
    float tt[8];
    #pragma unroll
    for (int j = 0; j < 8; ++j) tt[j] = 0.0f;
    #pragma unroll
    for (int d = 0; d < 32; ++d) {
        float x = ev[d];
        const float4 wa = *reinterpret_cast<const float4*>(w1 + (96 + d) * 16 + 8 * q);
        const float4 wb = *reinterpret_cast<const float4*>(w1 + (96 + d) * 16 + 8 * q + 4);
        tt[0] = fmaf(x, wa.x, tt[0]); tt[1] = fmaf(x, wa.y, tt[1]);
        tt[2] = fmaf(x, wa.z, tt[2]); tt[3] = fmaf(x, wa.w, tt[3]);
        tt[4] = fmaf(x, wb.x, tt[4]); tt[5] = fmaf(x, wb.y, tt[5]);
        tt[6] = fmaf(x, wb.z, tt[6]); tt[7] = fmaf(x, wb.w, tt[7]);
    }
    uint4 tw;
    tw.x = pack2(tt[0], tt[1]); tw.y = pack2(tt[2], tt[3]);
    tw.z = pack2(tt[4], tt[5]); tw.w = pack2(tt[6], tt[7]);
    *reinterpret_cast<uint4*>(rec + 4 * q) = tw;

    // thread q converts ie floats [16q .. 16q+15] -> words 8+8q ..
    {
        const float* src = ev + 16 * q;
        uint32_t* dst = rec + 8 + 8 * q;
        #pragma unroll
        for (int c = 0; c < 2; ++c) {
            uint4 o;
            o.x = pack2(src[8*c+0], src[8*c+1]);
            o.y = pack2(src[8*c+2], src[8*c+3]);
            o.z = pack2(src[8*c+4], src[8*c+5]);
            o.w = pack2(src[8*c+6], src[8*c+7]);
            *reinterpret_cast<uint4*>(dst + 4 * c) = o;
        }
    }
}

// ---------------- main: one thread per batch element, original order ----------------
// Issues ALL record loads up front (20 x uint4, statically indexed -> registers)
// so each wave keeps ~320B outstanding; then consumes. Coalesced gi/ii/out.
__global__ __launch_bounds__(256) void agree_main(
    const int* __restrict__ gi, const int* __restrict__ ii,
    const uint32_t* __restrict__ grec, const uint32_t* __restrict__ irec,
    const float* __restrict__ w2, const float* __restrict__ b2,
    const float* __restrict__ pw1, const float* __restrict__ pb1,
    const float* __restrict__ pw2, const float* __restrict__ pb2,
    float* __restrict__ out, int B)
{
    int b = blockIdx.x * 256 + threadIdx.x;
    if (b >= B) return;

    const uint4* gr4 = reinterpret_cast<const uint4*>(grec + (size_t)gi[b] * GRECW);
    const uint4* ir4 = reinterpret_cast<const uint4*>(irec + (size_t)ii[b] * IRECW);

    // ---- issue all loads before any use ----
    uint4 G[14];
    #pragma unroll
    for (int c = 0; c < 14; ++c) G[c] = gr4[c];
    uint4 I[6];
    #pragma unroll
    for (int c = 0; c < 6; ++c) I[c] = ir4[c];

    // h = relu(s + t)
    float h[16];
    #pragma unroll
    for (int c = 0; c < 2; ++c) {
        uint4 sa = G[c];
        uint4 ta = I[c];
        h[8*c+0] = fmaxf(BLO(sa.x) + BLO(ta.x), 0.0f);
        h[8*c+1] = fmaxf(BHI(sa.x) + BHI(ta.x), 0.0f);
        h[8*c+2] = fmaxf(BLO(sa.y) + BLO(ta.y), 0.0f);
        h[8*c+3] = fmaxf(BHI(sa.y) + BHI(ta.y), 0.0f);
        h[8*c+4] = fmaxf(BLO(sa.z) + BLO(ta.z), 0.0f);
        h[8*c+5] = fmaxf(BHI(sa.z) + BHI(ta.z), 0.0f);
        h[8*c+6] = fmaxf(BLO(sa.w) + BLO(ta.w), 0.0f);
        h[8*c+7] = fmaxf(BHI(sa.w) + BHI(ta.w), 0.0f);
    }

    // logits + softmax over 3 members
    float l0 = b2[0], l1 = b2[1], l2 = b2[2];
    #pragma unroll
    for (int j = 0; j < 16; ++j) {
        l0 = fmaf(h[j], w2[j * 3 + 0], l0);
        l1 = fmaf(h[j], w2[j * 3 + 1], l1);
        l2 = fmaf(h[j], w2[j * 3 + 2], l2);
    }
    float mx = fmaxf(l0, fmaxf(l1, l2));
    float e0 = __expf(l0 - mx);
    float e1 = __expf(l1 - mx);
    float e2 = __expf(l2 - mx);
    float inv = 1.0f / (e0 + e1 + e2);
    float wt0 = e0 * inv, wt1 = e1 * inv, wt2 = e2 * inv;

    // g = wt0*me0 + wt1*me1 + wt2*me2   (me0=G[2..5], me1=G[6..9], me2=G[10..13])
    float g[32];
    #pragma unroll
    for (int c = 0; c < 4; ++c) {
        uint4 a  = G[2 + c];
        uint4 bq = G[6 + c];
        uint4 cq = G[10 + c];
        g[8*c+0] = fmaf(wt0, BLO(a.x), fmaf(wt1, BLO(bq.x), wt2 * BLO(cq.x)));
        g[8*c+1] = fmaf(wt0, BHI(a.x), fmaf(wt1, BHI(bq.x), wt2 * BHI(cq.x)));
        g[8*c+2] = fmaf(wt0, BLO(a.y), fmaf(wt1, BLO(bq.y), wt2 * BLO(cq.y)));
        g[8*c+3] = fmaf(wt0, BHI(a.y), fmaf(wt1, BHI(bq.y), wt2 * BHI(cq.y)));
        g[8*c+4] = fmaf(wt0, BLO(a.z), fmaf(wt1, BLO(bq.z), wt2 * BLO(cq.z)));
        g[8*c+5] = fmaf(wt0, BHI(a.z), fmaf(wt1, BHI(bq.z), wt2 * BHI(cq.z)));
        g[8*c+6] = fmaf(wt0, BLO(a.w), fmaf(wt1, BLO(bq.w), wt2 * BLO(cq.w)));
        g[8*c+7] = fmaf(wt0, BHI(a.w), fmaf(wt1, BHI(bq.w), wt2 * BHI(cq.w)));
    }

    // h2[j] = pb1[j] + (g.*ie)@A + g@B + ie@C   (A=pw1 rows 0..31, B=32..63, C=64..95)
    float h2[8];
    #pragma unroll
    for (int j = 0; j < 8; ++j) h2[j] = pb1[j];

    #pragma unroll
    for (int c = 0; c < 4; ++c) {
        uint4 e4 = I[2 + c];
        float ef[8];
        ef[0] = BLO(e4.x); ef[1] = BHI(e4.x);
        ef[2] = BLO(e4.y); ef[3] = BHI(e4.y);
        ef[4] = BLO(e4.z); ef[5] = BHI(e4.z);
        ef[6] = BLO(e4.w); ef[7] = BHI(e4.w);
        #pragma unroll
        for (int r = 0; r < 8; ++r) {
            int d = 8 * c + r;
            float e  = ef[r];
            float gd = g[d];
            float ge = gd * e;
            #pragma unroll
            for (int j = 0; j < 8; ++j) {
                h2[j] = fmaf(ge, pw1[d * 8 + j],        h2[j]);
                h2[j] = fmaf(gd, pw1[(32 + d) * 8 + j], h2[j]);
                h2[j] = fmaf(e,  pw1[(64 + d) * 8 + j], h2[j]);
            }
        }
    }

    float z = pb2[0];
    #pragma unroll
    for (int j = 0; j < 8; ++j)
        z = fmaf(fmaxf(h2[j], 0.0f), pw2[j], z);

    out[b] = 1.0f / (1.0f + __expf(-z));
}

// ---------------- fallback (round-1 kernel) if ws too small ----------------
__global__ __launch_bounds__(256) void agree_fwd(
    const int* __restrict__ gi, const int* __restrict__ ii,
    const int* __restrict__ gm,
    const float* __restrict__ ue, const float* __restrict__ itemb,
    const float* __restrict__ w1, const float* __restrict__ b1,
    const float* __restrict__ w2, const float* __restrict__ b2,
    const float* __restrict__ pw1, const float* __restrict__ pb1,
    const float* __restrict__ pw2, const float* __restrict__ pb2,
    float* __restrict__ out, int B)
{
    int b = blockIdx.x * blockDim.x + threadIdx.x;
    if (b >= B) return;
    int g = gi[b], it = ii[b];
    int m0 = gm[3*g+0], m1 = gm[3*g+1], m2 = gm[3*g+2];
    float me[3][DD], iev[DD];
    {
        const float4* p0 = reinterpret_cast<const float4*>(ue + (size_t)m0 * DD);
        const float4* p1 = reinterpret_cast<const float4*>(ue + (size_t)m1 * DD);
        const float4* p2 = reinterpret_cast<const float4*>(ue + (size_t)m2 * DD);
        const float4* p3 = reinterpret_cast<const float4*>(itemb + (size_t)it * DD);
        #pragma unroll
        for (int c = 0; c < 8; ++c) {
            float4 v0 = p0[c], v1 = p1[c], v2 = p2[c], v3 = p3[c];
            me[0][4*c]=v0.x; me[0][4*c+1]=v0.y; me[0][4*c+2]=v0.z; me[0][4*c+3]=v0.w;
            me[1][4*c]=v1.x; me[1][4*c+1]=v1.y; me[1][4*c+2]=v1.z; me[1][4*c+3]=v1.w;
            me[2][4*c]=v2.x; me[2][4*c+1]=v2.y; me[2][4*c+2]=v2.z; me[2][4*c+3]=v2.w;
            iev[4*c]=v3.x; iev[4*c+1]=v3.y; iev[4*c+2]=v3.z; iev[4*c+3]=v3.w;
        }
    }
    float h[16];
    #pragma unroll
    for (int j = 0; j < 16; ++j) h[j] = b1[j];
    #pragma unroll
    for (int m = 0; m < 3; ++m)
        #pragma unroll
        for (int kk = 0; kk < DD; ++kk) {
            float xk = me[m][kk];
            #pragma unroll
            for (int j = 0; j < 16; ++j)
                h[j] = fmaf(xk, w1[(m*DD+kk)*16+j], h[j]);
        }
    #pragma unroll
    for (int kk = 0; kk < DD; ++kk) {
        float xk = iev[kk];
        #pragma unroll
        for (int j = 0; j < 16; ++j)
            h[j] = fmaf(xk, w1[(3*DD+kk)*16+j], h[j]);
    }
    #pragma unroll
    for (int j = 0; j < 16; ++j) h[j] = fmaxf(h[j], 0.0f);
    float l0 = b2[0], l1 = b2[1], l2 = b2[2];
    #pragma unroll
    for (int j = 0; j < 16; ++j) {
        l0 = fmaf(h[j], w2[j*3+0], l0);
        l1 = fmaf(h[j], w2[j*3+1], l1);
        l2 = fmaf(h[j], w2[j*3+2], l2);
    }
    float mx = fmaxf(l0, fmaxf(l1, l2));
    float e0 = __expf(l0-mx), e1 = __expf(l1-mx), e2 = __expf(l2-mx);
    float inv = 1.0f / (e0+e1+e2);
    float wt0 = e0*inv, wt1 = e1*inv, wt2 = e2*inv;
    float h2[8];
    #pragma unroll
    for (int j = 0; j < 8; ++j) h2[j] = pb1[j];
    #pragma unroll
    for (int d = 0; d < DD; ++d) {
        float gd  = wt0*me[0][d] + wt1*me[1][d] + wt2*me[2][d];
        float gie = gd * iev[d];
        #pragma unroll
        for (int j = 0; j < 8; ++j) {
            h2[j] = fmaf(gie,    pw1[d*8+j],          h2[j]);
            h2[j] = fmaf(gd,     pw1[(DD+d)*8+j],     h2[j]);
            h2[j] = fmaf(iev[d], pw1[(2*DD+d)*8+j],   h2[j]);
        }
    }
    float z = pb2[0];
    #pragma unroll
    for (int j = 0; j < 8; ++j)
        z = fmaf(fmaxf(h2[j], 0.0f), pw2[j], z);
    out[b] = 1.0f / (1.0f + __expf(-z));
}

extern "C" void kernel_launch(void* const* d_in, const int* in_sizes, int n_in,
                              void* d_out, int out_size, void* d_ws, size_t ws_size,
                              hipStream_t stream) {
    const int*   gi    = (const int*)d_in[0];
    const int*   ii    = (const int*)d_in[1];
    const int*   gm    = (const int*)d_in[2];
    const float* ue    = (const float*)d_in[3];
    const float* itemb = (const float*)d_in[4];
    const float* w1    = (const float*)d_in[5];
    const float* b1    = (const float*)d_in[6];
    const float* w2    = (const float*)d_in[7];
    const float* b2    = (const float*)d_in[8];
    const float* pw1   = (const float*)d_in[9];
    const float* pb1   = (const float*)d_in[10];
    const float* pw2   = (const float*)d_in[11];
    const float* pb2   = (const float*)d_in[12];
    float* out = (float*)d_out;

    int B  = in_sizes[0];
    int NG = in_sizes[2] / 3;
    int NI = in_sizes[4] / DD;

    size_t need = ((size_t)NG * GRECW + (size_t)NI * IRECW) * sizeof(uint32_t) + 512;
    if (ws_size >= need) {
        char* ws = (char*)d_ws;
        uint32_t* grec = (uint32_t*)ws;
        uint32_t* irec = grec + (((size_t)NG * GRECW + 63) & ~(size_t)63);

        hipLaunchKernelGGL(grp_pre, dim3((4 * NG + 255) / 256), dim3(256), 0, stream,
                           gm, ue, w1, b1, grec, NG);
        hipLaunchKernelGGL(item_pre, dim3((2 * NI + 255) / 256), dim3(256), 0, stream,
                           itemb, w1, irec, NI);
        hipLaunchKernelGGL(agree_main, dim3((B + 255) / 256), dim3(256), 0, stream,
                           gi, ii, grec, irec, w2, b2, pw1, pb1, pw2, pb2, out, B);
    } else {
        hipLaunchKernelGGL(agree_fwd, dim3((B + 255) / 256), dim3(256), 0, stream,
                           gi, ii, gm, ue, itemb, w1, b1, w2, b2,
                           pw1, pb1, pw2, pb2, out, B);
    }
}